// Round 1
// baseline (2270.390 us; speedup 1.0000x reference)
//
#include <hip/hip_runtime.h>
#include <math.h>

// Problem constants
// B=32, C=12, H=64, W=64, hidden=128, cond_c=4, out_spline=276=12*23
// NUM_BINS=8, TAIL=3.0, MBW=MBH=MD=0.001

#define NPIX 4096           // 64*64
#define NY   1572864        // 32*12*64*64

// ---------------------------------------------------------------------------
// prep: weight transposes (for contiguous scalar loads) + logdet init
//   w1 (128,16,3,3)  -> w1t[(ci*9+tap)*128 + oc]
//   w2 (128,128,1,1) -> w2t[ci*128 + oc]
//   w3 (276,128,3,3) -> w3t[((c*128+ci)*9+tap)*24 + j]   (j<23, pad to 24)
//   ld_out[b] = logdet[b]
// ---------------------------------------------------------------------------
__global__ __launch_bounds__(256) void prep_k(
    const float* __restrict__ w1, const float* __restrict__ w2,
    const float* __restrict__ w3, float* __restrict__ w1t,
    float* __restrict__ w2t, float* __restrict__ w3t,
    const float* __restrict__ logdet, float* __restrict__ ld_out)
{
    const int i = blockIdx.x * 256 + threadIdx.x;
    if (i < 18432) {                      // w1: oc*144 + (ci*9+tap)
        int oc = i / 144, r = i % 144;
        w1t[r * 128 + oc] = w1[i];
    }
    if (i < 16384) {                      // w2: oc*128 + ci
        int oc = i >> 7, ci = i & 127;
        w2t[ci * 128 + oc] = w2[i];
    }
    if (i < 12 * 128 * 9 * 24) {          // w3t flat index decomposition
        int j = i % 24;
        int rest = i / 24;
        int tap = rest % 9;
        int ci = (rest / 9) % 128;
        int c = rest / (9 * 128);
        w3t[i] = (j < 23) ? w3[((c * 23 + j) * 128 + ci) * 9 + tap] : 0.f;
    }
    if (i < 32) ld_out[i] = logdet[i];
}

// ---------------------------------------------------------------------------
// conv1: 3x3 SAME, in=concat(x[12], cond[4]), out=128, + bias + relu
// block = 64 threads (one W row), grid = (128/16, H, B); 16 oc per block.
// Weight addresses are blockIdx/loop-derived -> wave-uniform -> s_load.
// ---------------------------------------------------------------------------
__global__ __launch_bounds__(64) void conv1_k(
    const float* __restrict__ x, const float* __restrict__ cond,
    const float* __restrict__ w1t, const float* __restrict__ b1,
    float* __restrict__ h1)
{
    const int w = threadIdx.x;
    const int ocb = blockIdx.x * 16;
    const int h = blockIdx.y;
    const int b = blockIdx.z;

    float acc[16];
#pragma unroll
    for (int j = 0; j < 16; ++j) acc[j] = b1[ocb + j];

    for (int ci = 0; ci < 16; ++ci) {
        const float* src = (ci < 12) ? (x + ((size_t)(b * 12 + ci)) * NPIX)
                                     : (cond + ((size_t)(b * 4 + (ci - 12))) * NPIX);
#pragma unroll
        for (int dy = -1; dy <= 1; ++dy) {
            const int hh = h + dy;
            const bool hv = (hh >= 0) && (hh < 64);
#pragma unroll
            for (int dx = -1; dx <= 1; ++dx) {
                const int ww = w + dx;
                const float v = (hv && ww >= 0 && ww < 64) ? src[hh * 64 + ww] : 0.f;
                const float* wp = w1t + (ci * 9 + (dy + 1) * 3 + (dx + 1)) * 128 + ocb;
#pragma unroll
                for (int j = 0; j < 16; ++j) acc[j] = fmaf(v, wp[j], acc[j]);
            }
        }
    }
#pragma unroll
    for (int j = 0; j < 16; ++j)
        h1[(((size_t)(b * 128 + ocb + j)) << 12) + h * 64 + w] = fmaxf(acc[j], 0.f);
}

// ---------------------------------------------------------------------------
// conv2: 1x1, 128->128, + bias + relu
// block = 256 threads over pixels, grid = (128/16, 32*4096/256); 16 oc/block.
// ---------------------------------------------------------------------------
__global__ __launch_bounds__(256) void conv2_k(
    const float* __restrict__ h1, const float* __restrict__ w2t,
    const float* __restrict__ b2, float* __restrict__ h2)
{
    const int ocb = blockIdx.x * 16;
    const int pg = blockIdx.y * 256 + threadIdx.x;
    const int b = pg >> 12;
    const int p = pg & 4095;

    float acc[16];
#pragma unroll
    for (int j = 0; j < 16; ++j) acc[j] = b2[ocb + j];

    for (int ci = 0; ci < 128; ++ci) {
        const float v = h1[(((size_t)(b * 128 + ci)) << 12) + p];
        const float* wp = w2t + ci * 128 + ocb;
#pragma unroll
        for (int j = 0; j < 16; ++j) acc[j] = fmaf(v, wp[j], acc[j]);
    }
#pragma unroll
    for (int j = 0; j < 16; ++j)
        h2[(((size_t)(b * 128 + ocb + j)) << 12) + p] = fmaxf(acc[j], 0.f);
}

// ---------------------------------------------------------------------------
// conv3 (3x3, 128->276) fused with RQS spline + logdet reduction.
// One thread = one (b, c, h, w) element: accumulates its 23 spline params
// (oc = c*23 + j) in registers, then evaluates the spline inline.
// block = 64 threads (one W row), grid = (C=12, H=64, B=32).
// Per thread: 1152 coalesced h2 loads, 26496 FMAs (23 per load).
// ---------------------------------------------------------------------------
__global__ __launch_bounds__(64) void conv3_rqs_k(
    const float* __restrict__ h2, const float* __restrict__ w3t,
    const float* __restrict__ b3, const float* __restrict__ x,
    float* __restrict__ y, float* __restrict__ ld_out)
{
    const int w = threadIdx.x;
    const int c = blockIdx.x;
    const int h = blockIdx.y;
    const int b = blockIdx.z;

    float acc[23];
#pragma unroll
    for (int j = 0; j < 23; ++j) acc[j] = b3[c * 23 + j];

    const float* wbase = w3t + (size_t)c * 128 * 9 * 24;

    for (int ci = 0; ci < 128; ++ci) {
        const float* hb = h2 + (((size_t)(b * 128 + ci)) << 12);
        const float* wci = wbase + ci * 9 * 24;
#pragma unroll
        for (int dy = -1; dy <= 1; ++dy) {
            const int hh = h + dy;
            const bool hv = (hh >= 0) && (hh < 64);
#pragma unroll
            for (int dx = -1; dx <= 1; ++dx) {
                const int ww = w + dx;
                const float v = (hv && ww >= 0 && ww < 64) ? hb[hh * 64 + ww] : 0.f;
                const float* wp = wci + ((dy + 1) * 3 + (dx + 1)) * 24;
#pragma unroll
                for (int j = 0; j < 23; ++j) acc[j] = fmaf(v, wp[j], acc[j]);
            }
        }
    }

    // ---- RQS spline ----
    const size_t eidx = (((size_t)(b * 12 + c)) << 12) + h * 64 + w;
    const float xv = x[eidx];
    const float xin = fminf(fmaxf(xv, -3.f), 3.f);

    // softmax numerators for widths (acc[0..7]) and heights (acc[8..15])
    float mw = acc[0], mh = acc[8];
#pragma unroll
    for (int j = 1; j < 8; ++j) { mw = fmaxf(mw, acc[j]); mh = fmaxf(mh, acc[8 + j]); }
    float ew[8], eh[8];
    float sw = 0.f, sh = 0.f;
#pragma unroll
    for (int j = 0; j < 8; ++j) {
        ew[j] = expf(acc[j] - mw);      sw += ew[j];
        eh[j] = expf(acc[8 + j] - mh);  sh += eh[j];
    }
    const float rw = 1.f / sw, rh = 1.f / sh;

    const float CONST_D = logf(expf(0.999f) - 1.f);   // pad value for derivs

    // streaming bin search + select (branch-free, fully unrolled)
    float cumw = 0.f, cumh = 0.f;
    float cw_lo = -3.f, ch_lo = -3.f;
    float in_cw = 0.f, in_w = 1.f, in_ch = 0.f, in_h = 1.f, sd0 = 0.f, sd1 = 0.f;
#pragma unroll
    for (int i = 0; i < 8; ++i) {
        cumw += fmaf(0.992f, ew[i] * rw, 0.001f);
        cumh += fmaf(0.992f, eh[i] * rh, 0.001f);
        const float cw_hi = (i == 7) ? 3.f : fmaf(6.f, cumw, -3.f);
        const float ch_hi = (i == 7) ? 3.f : fmaf(6.f, cumh, -3.f);
        const bool sel = (xin >= cw_lo) && ((i == 7) || (xin < cw_hi));
        in_cw = sel ? cw_lo : in_cw;
        in_w  = sel ? (cw_hi - cw_lo) : in_w;
        in_ch = sel ? ch_lo : in_ch;
        in_h  = sel ? (ch_hi - ch_lo) : in_h;
        sd0   = sel ? ((i == 0) ? CONST_D : acc[16 + i - 1]) : sd0;
        sd1   = sel ? ((i == 7) ? CONST_D : acc[16 + i]) : sd1;
        cw_lo = cw_hi; ch_lo = ch_hi;
    }

    // softplus derivs
    const float d0 = 0.001f + ((sd0 > 20.f) ? sd0 : log1pf(expf(sd0)));
    const float d1 = 0.001f + ((sd1 > 20.f) ? sd1 : log1pf(expf(sd1)));

    const float delta = in_h / in_w;
    const float theta = (xin - in_cw) / in_w;
    const float omt = 1.f - theta;
    const float tom = theta * omt;
    const float th2 = theta * theta;
    const float numer = in_h * (delta * th2 + d0 * tom);
    const float denom = delta + (d0 + d1 - 2.f * delta) * tom;
    float yv = in_ch + numer / denom;
    const float dnum = delta * delta * (d1 * th2 + 2.f * delta * tom + d0 * omt * omt);
    float lad = logf(dnum) - 2.f * logf(denom);

    const bool inside = (xv >= -3.f) && (xv <= 3.f);
    yv = inside ? yv : xv;
    lad = inside ? lad : 0.f;

    y[eidx] = yv;

    // wave-64 reduction of lad, one atomic per wave into logdet[b]
#pragma unroll
    for (int off = 32; off > 0; off >>= 1) lad += __shfl_down(lad, off);
    if (threadIdx.x == 0) atomicAdd(&ld_out[b], lad);
}

// ---------------------------------------------------------------------------
extern "C" void kernel_launch(void* const* d_in, const int* in_sizes, int n_in,
                              void* d_out, int out_size, void* d_ws, size_t ws_size,
                              hipStream_t stream)
{
    const float* x      = (const float*)d_in[0];
    const float* logdet = (const float*)d_in[1];
    const float* cond   = (const float*)d_in[2];
    const float* w1     = (const float*)d_in[3];
    const float* b1     = (const float*)d_in[4];
    const float* w2     = (const float*)d_in[5];
    const float* b2     = (const float*)d_in[6];
    const float* w3     = (const float*)d_in[7];
    const float* b3     = (const float*)d_in[8];

    float* ws = (float*)d_ws;
    float* h1  = ws;                                   // 2^24 floats (64 MiB)
    float* h2  = ws + ((size_t)1 << 24);               // 2^24 floats (64 MiB)
    float* w1t = ws + ((size_t)2 << 24);               // 18432 floats
    float* w2t = w1t + 18432;                          // 16384 floats
    float* w3t = w2t + 16384;                          // 331776 floats

    float* y      = (float*)d_out;                     // NY floats
    float* ld_out = y + NY;                            // 32 floats

    prep_k<<<1296, 256, 0, stream>>>(w1, w2, w3, w1t, w2t, w3t, logdet, ld_out);
    conv1_k<<<dim3(8, 64, 32), 64, 0, stream>>>(x, cond, w1t, b1, h1);
    conv2_k<<<dim3(8, 512), 256, 0, stream>>>(h1, w2t, b2, h2);
    conv3_rqs_k<<<dim3(12, 64, 32), 64, 0, stream>>>(h2, w3t, b3, x, y, ld_out);
}

// Round 2
// 1368.891 us; speedup vs baseline: 1.6586x; 1.6586x over previous
//
#include <hip/hip_runtime.h>
#include <math.h>

// Problem constants
// B=32, C=12, H=64, W=64, hidden=128, cond_c=4, out_spline=276=12*23
// NUM_BINS=8, TAIL=3.0, MBW=MBH=MD=0.001

#define NPIX 4096           // 64*64
#define NY   1572864        // 32*12*64*64

// ---------------------------------------------------------------------------
// prep: weight transposes (for contiguous scalar loads) + logdet init
//   w1 (128,16,3,3)  -> w1t[(ci*9+tap)*128 + oc]
//   w2 (128,128,1,1) -> w2t[ci*128 + oc]
//   w3 (276,128,3,3) -> w3t[((c*128+ci)*9+tap)*24 + j]   (j<23, pad to 24)
//   ld_out[b] = logdet[b]
// ---------------------------------------------------------------------------
__global__ __launch_bounds__(256) void prep_k(
    const float* __restrict__ w1, const float* __restrict__ w2,
    const float* __restrict__ w3, float* __restrict__ w1t,
    float* __restrict__ w2t, float* __restrict__ w3t,
    const float* __restrict__ logdet, float* __restrict__ ld_out)
{
    const int i = blockIdx.x * 256 + threadIdx.x;
    if (i < 18432) {                      // w1: oc*144 + (ci*9+tap)
        int oc = i / 144, r = i % 144;
        w1t[r * 128 + oc] = w1[i];
    }
    if (i < 16384) {                      // w2: oc*128 + ci
        int oc = i >> 7, ci = i & 127;
        w2t[ci * 128 + oc] = w2[i];
    }
    if (i < 12 * 128 * 9 * 24) {          // w3t flat index decomposition
        int j = i % 24;
        int rest = i / 24;
        int tap = rest % 9;
        int ci = (rest / 9) % 128;
        int c = rest / (9 * 128);
        w3t[i] = (j < 23) ? w3[((c * 23 + j) * 128 + ci) * 9 + tap] : 0.f;
    }
    if (i < 32) ld_out[i] = logdet[i];
}

// ---------------------------------------------------------------------------
// conv1: 3x3 SAME, in=concat(x[12], cond[4]), out=128, + bias + relu
// ---------------------------------------------------------------------------
__global__ __launch_bounds__(64) void conv1_k(
    const float* __restrict__ x, const float* __restrict__ cond,
    const float* __restrict__ w1t, const float* __restrict__ b1,
    float* __restrict__ h1)
{
    const int w = threadIdx.x;
    const int ocb = blockIdx.x * 16;
    const int h = blockIdx.y;
    const int b = blockIdx.z;

    float acc[16];
#pragma unroll
    for (int j = 0; j < 16; ++j) acc[j] = b1[ocb + j];

    for (int ci = 0; ci < 16; ++ci) {
        const float* src = (ci < 12) ? (x + ((size_t)(b * 12 + ci)) * NPIX)
                                     : (cond + ((size_t)(b * 4 + (ci - 12))) * NPIX);
#pragma unroll
        for (int dy = -1; dy <= 1; ++dy) {
            const int hh = h + dy;
            const bool hv = (hh >= 0) && (hh < 64);
#pragma unroll
            for (int dx = -1; dx <= 1; ++dx) {
                const int ww = w + dx;
                const float v = (hv && ww >= 0 && ww < 64) ? src[hh * 64 + ww] : 0.f;
                const float* wp = w1t + (ci * 9 + (dy + 1) * 3 + (dx + 1)) * 128 + ocb;
#pragma unroll
                for (int j = 0; j < 16; ++j) acc[j] = fmaf(v, wp[j], acc[j]);
            }
        }
    }
#pragma unroll
    for (int j = 0; j < 16; ++j)
        h1[(((size_t)(b * 128 + ocb + j)) << 12) + h * 64 + w] = fmaxf(acc[j], 0.f);
}

// ---------------------------------------------------------------------------
// conv2: 1x1, 128->128, + bias + relu
// ---------------------------------------------------------------------------
__global__ __launch_bounds__(256) void conv2_k(
    const float* __restrict__ h1, const float* __restrict__ w2t,
    const float* __restrict__ b2, float* __restrict__ h2)
{
    const int ocb = blockIdx.x * 16;
    const int pg = blockIdx.y * 256 + threadIdx.x;
    const int b = pg >> 12;
    const int p = pg & 4095;

    float acc[16];
#pragma unroll
    for (int j = 0; j < 16; ++j) acc[j] = b2[ocb + j];

    for (int ci = 0; ci < 128; ++ci) {
        const float v = h1[(((size_t)(b * 128 + ci)) << 12) + p];
        const float* wp = w2t + ci * 128 + ocb;
#pragma unroll
        for (int j = 0; j < 16; ++j) acc[j] = fmaf(v, wp[j], acc[j]);
    }
#pragma unroll
    for (int j = 0; j < 16; ++j)
        h2[(((size_t)(b * 128 + ocb + j)) << 12) + p] = fmaxf(acc[j], 0.f);
}

// ---------------------------------------------------------------------------
// RQS spline evaluation for one element, given its 23 params in acc[].
// ---------------------------------------------------------------------------
__device__ __forceinline__ void rqs_eval(const float* acc, float xv,
                                         float& yv_out, float& lad_out)
{
    const float xin = fminf(fmaxf(xv, -3.f), 3.f);

    float mw = acc[0], mh = acc[8];
#pragma unroll
    for (int j = 1; j < 8; ++j) { mw = fmaxf(mw, acc[j]); mh = fmaxf(mh, acc[8 + j]); }
    float ew[8], eh[8];
    float sw = 0.f, sh = 0.f;
#pragma unroll
    for (int j = 0; j < 8; ++j) {
        ew[j] = expf(acc[j] - mw);      sw += ew[j];
        eh[j] = expf(acc[8 + j] - mh);  sh += eh[j];
    }
    const float rw = 1.f / sw, rh = 1.f / sh;

    const float CONST_D = logf(expf(0.999f) - 1.f);

    float cumw = 0.f, cumh = 0.f;
    float cw_lo = -3.f, ch_lo = -3.f;
    float in_cw = 0.f, in_w = 1.f, in_ch = 0.f, in_h = 1.f, sd0 = 0.f, sd1 = 0.f;
#pragma unroll
    for (int i = 0; i < 8; ++i) {
        cumw += fmaf(0.992f, ew[i] * rw, 0.001f);
        cumh += fmaf(0.992f, eh[i] * rh, 0.001f);
        const float cw_hi = (i == 7) ? 3.f : fmaf(6.f, cumw, -3.f);
        const float ch_hi = (i == 7) ? 3.f : fmaf(6.f, cumh, -3.f);
        const bool sel = (xin >= cw_lo) && ((i == 7) || (xin < cw_hi));
        in_cw = sel ? cw_lo : in_cw;
        in_w  = sel ? (cw_hi - cw_lo) : in_w;
        in_ch = sel ? ch_lo : in_ch;
        in_h  = sel ? (ch_hi - ch_lo) : in_h;
        sd0   = sel ? ((i == 0) ? CONST_D : acc[16 + i - 1]) : sd0;
        sd1   = sel ? ((i == 7) ? CONST_D : acc[16 + i]) : sd1;
        cw_lo = cw_hi; ch_lo = ch_hi;
    }

    const float d0 = 0.001f + ((sd0 > 20.f) ? sd0 : log1pf(expf(sd0)));
    const float d1 = 0.001f + ((sd1 > 20.f) ? sd1 : log1pf(expf(sd1)));

    const float delta = in_h / in_w;
    const float theta = (xin - in_cw) / in_w;
    const float omt = 1.f - theta;
    const float tom = theta * omt;
    const float th2 = theta * theta;
    const float numer = in_h * (delta * th2 + d0 * tom);
    const float denom = delta + (d0 + d1 - 2.f * delta) * tom;
    float yv = in_ch + numer / denom;
    const float dnum = delta * delta * (d1 * th2 + 2.f * delta * tom + d0 * omt * omt);
    float lad = logf(dnum) - 2.f * logf(denom);

    const bool inside = (xv >= -3.f) && (xv <= 3.f);
    yv_out = inside ? yv : xv;
    lad_out = inside ? lad : 0.f;
}

// ---------------------------------------------------------------------------
// conv3 (3x3, 128->276) fused with RQS + logdet.  v2: 4-row register blocking.
// block = 64 threads (one wave = one W row). Each thread owns 4 output rows
// (h0..h0+3) at its column w, for one channel c: acc[4][23] = 92 VGPRs.
// Per ci: 6 coalesced row loads, 12 shuffles for w+-1, 828 FMAs.
// Weights are wave-uniform (readfirstlane-forced) -> s_load, scalar pipe.
// grid = (C=12, H/4=16, B=32) = 6144 waves.
// ---------------------------------------------------------------------------
__global__ __launch_bounds__(64) void conv3_rqs_k(
    const float* __restrict__ h2, const float* __restrict__ w3t,
    const float* __restrict__ b3, const float* __restrict__ x,
    float* __restrict__ y, float* __restrict__ ld_out)
{
    const int w = threadIdx.x;         // 0..63
    const int c = blockIdx.x;          // 0..11
    const int h0 = blockIdx.y * 4;     // 0,4,...,60
    const int b = blockIdx.z;

    float acc[4][23];
#pragma unroll
    for (int j = 0; j < 23; ++j) {
        const float bj = b3[c * 23 + j];
#pragma unroll
        for (int r = 0; r < 4; ++r) acc[r][j] = bj;
    }

    // staged rows h0-1 .. h0+4: element offsets + validity masks (constant over ci)
    int roff[6];
    float rmask[6];
#pragma unroll
    for (int k = 0; k < 6; ++k) {
        const int rr = h0 - 1 + k;
        const bool v = (rr >= 0) && (rr < 64);
        roff[k] = (v ? rr : 0) * 64 + w;
        rmask[k] = v ? 1.f : 0.f;
    }

    const int hbase = __builtin_amdgcn_readfirstlane((b * 128) << 12);
    const int wbase = __builtin_amdgcn_readfirstlane(c * 128 * 216);  // 9*24=216

    for (int ci = 0; ci < 128; ++ci) {
        const float* hb = h2 + hbase + (ci << 12);
        float v0[6], vl[6], vr[6];
#pragma unroll
        for (int k = 0; k < 6; ++k) v0[k] = hb[roff[k]] * rmask[k];
#pragma unroll
        for (int k = 0; k < 6; ++k) {
            const float l = __shfl_up(v0[k], 1);
            const float r = __shfl_down(v0[k], 1);
            vl[k] = (w == 0) ? 0.f : l;
            vr[k] = (w == 63) ? 0.f : r;
        }
        const float* wci = w3t + wbase + ci * 216;
#pragma unroll
        for (int dy = 0; dy < 3; ++dy) {
#pragma unroll
            for (int dx = 0; dx < 3; ++dx) {
                const float* wp = wci + (dy * 3 + dx) * 24;
#pragma unroll
                for (int r = 0; r < 4; ++r) {
                    const float val = (dx == 0) ? vl[r + dy]
                                    : (dx == 1) ? v0[r + dy] : vr[r + dy];
#pragma unroll
                    for (int j = 0; j < 23; ++j)
                        acc[r][j] = fmaf(val, wp[j], acc[r][j]);
                }
            }
        }
    }

    // ---- RQS spline on the 4 rows ----
    float lad_sum = 0.f;
#pragma unroll
    for (int r = 0; r < 4; ++r) {
        const size_t eidx = (((size_t)(b * 12 + c)) << 12) + (h0 + r) * 64 + w;
        const float xv = x[eidx];
        float yv, lad;
        rqs_eval(acc[r], xv, yv, lad);
        y[eidx] = yv;
        lad_sum += lad;
    }

    // wave-64 reduction, one atomic per wave
#pragma unroll
    for (int off = 32; off > 0; off >>= 1) lad_sum += __shfl_down(lad_sum, off);
    if (threadIdx.x == 0) atomicAdd(&ld_out[b], lad_sum);
}

// ---------------------------------------------------------------------------
extern "C" void kernel_launch(void* const* d_in, const int* in_sizes, int n_in,
                              void* d_out, int out_size, void* d_ws, size_t ws_size,
                              hipStream_t stream)
{
    const float* x      = (const float*)d_in[0];
    const float* logdet = (const float*)d_in[1];
    const float* cond   = (const float*)d_in[2];
    const float* w1     = (const float*)d_in[3];
    const float* b1     = (const float*)d_in[4];
    const float* w2     = (const float*)d_in[5];
    const float* b2     = (const float*)d_in[6];
    const float* w3     = (const float*)d_in[7];
    const float* b3     = (const float*)d_in[8];

    float* ws = (float*)d_ws;
    float* h1  = ws;                                   // 2^24 floats (64 MiB)
    float* h2  = ws + ((size_t)1 << 24);               // 2^24 floats (64 MiB)
    float* w1t = ws + ((size_t)2 << 24);               // 18432 floats
    float* w2t = w1t + 18432;                          // 16384 floats
    float* w3t = w2t + 16384;                          // 331776 floats

    float* y      = (float*)d_out;                     // NY floats
    float* ld_out = y + NY;                            // 32 floats

    prep_k<<<1296, 256, 0, stream>>>(w1, w2, w3, w1t, w2t, w3t, logdet, ld_out);
    conv1_k<<<dim3(8, 64, 32), 64, 0, stream>>>(x, cond, w1t, b1, h1);
    conv2_k<<<dim3(8, 512), 256, 0, stream>>>(h1, w2t, b2, h2);
    conv3_rqs_k<<<dim3(12, 16, 32), 64, 0, stream>>>(h2, w3t, b3, x, y, ld_out);
}

// Round 3
// 761.435 us; speedup vs baseline: 2.9817x; 1.7978x over previous
//
#include <hip/hip_runtime.h>
#include <math.h>

// B=32, C=12, H=64, W=64, hidden=128, cond_c=4, out_spline=276 (pad->288=12*24)
// NUM_BINS=8, TAIL=3.0, MBW=MBH=MD=0.001

#define NPIX 4096
#define NY   1572864

typedef _Float16 half8 __attribute__((ext_vector_type(8)));
typedef float f32x4 __attribute__((ext_vector_type(4)));

// async global->LDS, 16B per lane: LDS dest = ldst + lane*16, gsrc is per-lane
#define ASYNC16(gsrc, ldst) \
  __builtin_amdgcn_global_load_lds((const __attribute__((address_space(1))) unsigned int*)(gsrc), \
                                   (__attribute__((address_space(3))) unsigned int*)(ldst), 16, 0, 0)

// h2p layout: [b][cc=ci/32][pp=66*66][ci%32] fp16, halo ring of zeros
#define H2P_PLANE 4356            // 66*66
#define H2P_IDX(b, cc, pp) ((((size_t)(b) * 4 + (cc)) * H2P_PLANE + (pp)) << 5)

// ---------------------------------------------------------------------------
// prep: weight transposes + fp16 weight pack + logdet init
//   w1 (128,16,3,3)  -> w1t[(ci*9+tap)*128 + oc]                       fp32
//   w2 (128,128,1,1) -> w2t[ci*128 + oc]                               fp32
//   w3 (276,128,3,3) -> w3h[((t*4+cc)*288 + oc')*32 + cim]             fp16
//                       oc' = c*24 + j (j<23 real, j=23 zero pad)
// ---------------------------------------------------------------------------
__global__ __launch_bounds__(256) void prep_k(
    const float* __restrict__ w1, const float* __restrict__ w2,
    const float* __restrict__ w3, float* __restrict__ w1t,
    float* __restrict__ w2t, _Float16* __restrict__ w3h,
    const float* __restrict__ logdet, float* __restrict__ ld_out)
{
    const int i = blockIdx.x * 256 + threadIdx.x;   // < 331776
    if (i < 18432) {
        int oc = i / 144, r = i % 144;
        w1t[r * 128 + oc] = w1[i];
    }
    if (i < 16384) {
        int oc = i >> 7, ci = i & 127;
        w2t[ci * 128 + oc] = w2[i];
    }
    {   // w3h: flat i = ((t*4+cc)*288 + oc)*32 + cim
        int cim = i & 31;
        int oc = (i >> 5) % 288;
        int tc = i / (288 * 32);        // 0..35
        int t = tc >> 2, cc = tc & 3;
        int c = oc / 24, j = oc % 24;
        int ci = cc * 32 + cim;
        float v = (j < 23) ? w3[((c * 23 + j) * 128 + ci) * 9 + t] : 0.f;
        w3h[i] = (_Float16)v;
    }
    if (i < 32) ld_out[i] = logdet[i];
}

// ---------------------------------------------------------------------------
// zero the halo ring of h2p (260 border pixels per (b,cc) plane)
// threads: 32 b * 4 cc * 260 ring * 4 chunks16B = 133120
// ---------------------------------------------------------------------------
__global__ __launch_bounds__(256) void zring_k(_Float16* __restrict__ h2p)
{
    const int i = blockIdx.x * 256 + threadIdx.x;
    if (i >= 133120) return;
    const int q = i & 3;
    const int rest = i >> 2;
    const int r = rest % 260;
    const int cc = (rest / 260) & 3;
    const int b = rest / 1040;
    int pp;
    if (r < 66)       pp = r;                        // top row
    else if (r < 132) pp = 65 * 66 + (r - 66);       // bottom row
    else if (r < 196) pp = (r - 131) * 66;           // left col, rows 1..64
    else              pp = (r - 195) * 66 + 65;      // right col, rows 1..64
    f32x4 z = {0.f, 0.f, 0.f, 0.f};
    *(f32x4*)(h2p + H2P_IDX(b, cc, pp) + q * 8) = z;
}

// ---------------------------------------------------------------------------
// conv1: 3x3 SAME, in=concat(x[12], cond[4]), out=128, +bias+relu -> h1h fp16
// h1h layout [b][oc][pix]
// ---------------------------------------------------------------------------
__global__ __launch_bounds__(64) void conv1_k(
    const float* __restrict__ x, const float* __restrict__ cond,
    const float* __restrict__ w1t, const float* __restrict__ b1,
    _Float16* __restrict__ h1h)
{
    const int w = threadIdx.x;
    const int ocb = blockIdx.x * 16;
    const int h = blockIdx.y;
    const int b = blockIdx.z;

    float acc[16];
#pragma unroll
    for (int j = 0; j < 16; ++j) acc[j] = b1[ocb + j];

    for (int ci = 0; ci < 16; ++ci) {
        const float* src = (ci < 12) ? (x + ((size_t)(b * 12 + ci)) * NPIX)
                                     : (cond + ((size_t)(b * 4 + (ci - 12))) * NPIX);
#pragma unroll
        for (int dy = -1; dy <= 1; ++dy) {
            const int hh = h + dy;
            const bool hv = (hh >= 0) && (hh < 64);
#pragma unroll
            for (int dx = -1; dx <= 1; ++dx) {
                const int ww = w + dx;
                const float v = (hv && ww >= 0 && ww < 64) ? src[hh * 64 + ww] : 0.f;
                const float* wp = w1t + (ci * 9 + (dy + 1) * 3 + (dx + 1)) * 128 + ocb;
#pragma unroll
                for (int j = 0; j < 16; ++j) acc[j] = fmaf(v, wp[j], acc[j]);
            }
        }
    }
#pragma unroll
    for (int j = 0; j < 16; ++j)
        h1h[(((size_t)(b * 128 + ocb + j)) << 12) + h * 64 + w] = (_Float16)fmaxf(acc[j], 0.f);
}

// ---------------------------------------------------------------------------
// conv2: 1x1, 128->128, +bias+relu; reads h1h fp16, writes h2p fp16 (padded)
// thread = (16-oc block, pixel). 16 oc = half of one 32-ci chunk.
// ---------------------------------------------------------------------------
__global__ __launch_bounds__(256) void conv2_k(
    const _Float16* __restrict__ h1h, const float* __restrict__ w2t,
    const float* __restrict__ b2, _Float16* __restrict__ h2p)
{
    const int ocb = blockIdx.x * 16;
    const int pg = blockIdx.y * 256 + threadIdx.x;
    const int b = pg >> 12;
    const int p = pg & 4095;

    float acc[16];
#pragma unroll
    for (int j = 0; j < 16; ++j) acc[j] = b2[ocb + j];

    for (int ci = 0; ci < 128; ++ci) {
        const float v = (float)h1h[(((size_t)(b * 128 + ci)) << 12) + p];
        const float* wp = w2t + ci * 128 + ocb;
#pragma unroll
        for (int j = 0; j < 16; ++j) acc[j] = fmaf(v, wp[j], acc[j]);
    }

    const int h = p >> 6, w = p & 63;
    const int pp = (h + 1) * 66 + (w + 1);
    const int cc = ocb >> 5;
    _Float16 tmp[16];
#pragma unroll
    for (int j = 0; j < 16; ++j) tmp[j] = (_Float16)fmaxf(acc[j], 0.f);
    _Float16* dst = h2p + H2P_IDX(b, cc, pp) + (ocb & 31);
    *(f32x4*)(dst)     = *(f32x4*)(tmp);
    *(f32x4*)(dst + 8) = *(f32x4*)(tmp + 8);
}

// ---------------------------------------------------------------------------
// RQS spline evaluation for one element, given its 23 params in prm[].
// ---------------------------------------------------------------------------
__device__ __forceinline__ void rqs_eval(const float* prm, float xv,
                                         float& yv_out, float& lad_out)
{
    const float xin = fminf(fmaxf(xv, -3.f), 3.f);

    float mw = prm[0], mh = prm[8];
#pragma unroll
    for (int j = 1; j < 8; ++j) { mw = fmaxf(mw, prm[j]); mh = fmaxf(mh, prm[8 + j]); }
    float ew[8], eh[8];
    float sw = 0.f, sh = 0.f;
#pragma unroll
    for (int j = 0; j < 8; ++j) {
        ew[j] = expf(prm[j] - mw);      sw += ew[j];
        eh[j] = expf(prm[8 + j] - mh);  sh += eh[j];
    }
    const float rw = 1.f / sw, rh = 1.f / sh;

    const float CONST_D = logf(expf(0.999f) - 1.f);

    float cumw = 0.f, cumh = 0.f;
    float cw_lo = -3.f, ch_lo = -3.f;
    float in_cw = 0.f, in_w = 1.f, in_ch = 0.f, in_h = 1.f, sd0 = 0.f, sd1 = 0.f;
#pragma unroll
    for (int i = 0; i < 8; ++i) {
        cumw += fmaf(0.992f, ew[i] * rw, 0.001f);
        cumh += fmaf(0.992f, eh[i] * rh, 0.001f);
        const float cw_hi = (i == 7) ? 3.f : fmaf(6.f, cumw, -3.f);
        const float ch_hi = (i == 7) ? 3.f : fmaf(6.f, cumh, -3.f);
        const bool sel = (xin >= cw_lo) && ((i == 7) || (xin < cw_hi));
        in_cw = sel ? cw_lo : in_cw;
        in_w  = sel ? (cw_hi - cw_lo) : in_w;
        in_ch = sel ? ch_lo : in_ch;
        in_h  = sel ? (ch_hi - ch_lo) : in_h;
        sd0   = sel ? ((i == 0) ? CONST_D : prm[16 + i - 1]) : sd0;
        sd1   = sel ? ((i == 7) ? CONST_D : prm[16 + i]) : sd1;
        cw_lo = cw_hi; ch_lo = ch_hi;
    }

    const float d0 = 0.001f + ((sd0 > 20.f) ? sd0 : log1pf(expf(sd0)));
    const float d1 = 0.001f + ((sd1 > 20.f) ? sd1 : log1pf(expf(sd1)));

    const float delta = in_h / in_w;
    const float theta = (xin - in_cw) / in_w;
    const float omt = 1.f - theta;
    const float tom = theta * omt;
    const float th2 = theta * theta;
    const float numer = in_h * (delta * th2 + d0 * tom);
    const float denom = delta + (d0 + d1 - 2.f * delta) * tom;
    float yv = in_ch + numer / denom;
    const float dnum = delta * delta * (d1 * th2 + 2.f * delta * tom + d0 * omt * omt);
    float lad = logf(dnum) - 2.f * logf(denom);

    const bool inside = (xv >= -3.f) && (xv <= 3.f);
    yv_out = inside ? yv : xv;
    lad_out = inside ? lad : 0.f;
}

// ---------------------------------------------------------------------------
// conv3 as implicit-GEMM MFMA (fp16 in, fp32 acc) fused with RQS + logdet.
// GEMM: M=pixels (tile 256), N=oc' 288 (2 cols x 144), K=1152 (9 taps x 128 ci)
// WG = 256 threads (4 waves). Wave w: pixels [w*64, w*64+64) x 144 oc'
//   = 4 pix-tiles x 9 oc-tiles of 16x16x32 MFMA; acc = 144 VGPRs.
// K-loop: 18 steps of BK=64 (two 32-ci sub-tiles), m97 2-barrier structure,
// global_load_lds(16B) staging from halo-padded h2p (no border masks).
// Epilogue: per pix-tile, C -> LDS (wave-private), re-read 23 params/pixel,
// rqs_eval, y store, wave-reduced atomicAdd of logdet.
// ---------------------------------------------------------------------------
__global__ __launch_bounds__(256, 2) void conv3_rqs_k(
    const _Float16* __restrict__ h2p, const _Float16* __restrict__ w3h,
    const float* __restrict__ b3, const float* __restrict__ x,
    float* __restrict__ y, float* __restrict__ ld_out)
{
    // LDS map (bytes):
    //   staging: act0 [0,16384) act1 [16384,32768) wt0 [32768,41984) wt1 [41984,51200)
    //   epilogue (union with staging): epi 4 x 9216 = [0, 36864)
    //   b3l: [51200, 51776)
    __shared__ __align__(16) char smem[51776];

    const int tid = threadIdx.x;
    const int wv = tid >> 6, lane = tid & 63;
    const int row16 = lane & 15, quad = lane >> 4;
    const int col = blockIdx.x;            // 0..1 -> oc' base col*144, channels col*6..+5
    const int pix0 = blockIdx.y << 8;      // global pixel base (256-tile)
    const int b = pix0 >> 12;
    const int pim0 = pix0 & 4095;          // within-image
    const int h0 = pim0 >> 6;              // base row (multiple of 4)

    float* b3l = (float*)(smem + 51200);
    if (tid < 144) {
        const int c = tid / 24, j = tid % 24;
        b3l[tid] = (j < 23) ? b3[(col * 6 + c) * 23 + j] : 0.f;
    }

    f32x4 acc[4][9];
#pragma unroll
    for (int pt = 0; pt < 4; ++pt)
#pragma unroll
        for (int ot = 0; ot < 9; ++ot) acc[pt][ot] = (f32x4){0.f, 0.f, 0.f, 0.f};

    for (int t = 0; t < 9; ++t) {
        const int dy = t / 3 - 1, dx = t % 3 - 1;
        const int prow = h0 + wv + dy + 1;                 // padded row this wave stages
        const int pcol = dx + 1;
        for (int cch = 0; cch < 2; ++cch) {
            // ---- stage two 32-ci sub-tiles (act: 4 rows x 64 pix x 32ci each) ----
#pragma unroll
            for (int s = 0; s < 2; ++s) {
                const int cc = cch * 2 + s;
                const _Float16* g = h2p + H2P_IDX(b, cc, prow * 66 + pcol);
#pragma unroll
                for (int i = 0; i < 4; ++i)
                    ASYNC16(g + i * 512 + lane * 8, smem + s * 16384 + wv * 4096 + i * 1024);
                const _Float16* gw = w3h + ((((t * 4 + cc) * 288) + col * 144) << 5);
                for (int i = wv; i < 9; i += 4)
                    ASYNC16(gw + i * 512 + lane * 8, smem + 32768 + s * 9216 + i * 1024);
            }
            __syncthreads();
            // ---- compute: 2 sub-tiles x (4 pix-tiles x 9 oc-tiles) ----
#pragma unroll
            for (int s = 0; s < 2; ++s) {
                const _Float16* act = (const _Float16*)(smem + s * 16384);
                const _Float16* wt  = (const _Float16*)(smem + 32768 + s * 9216);
                half8 bf[4];
#pragma unroll
                for (int pt = 0; pt < 4; ++pt)
                    bf[pt] = *(const half8*)(act + ((wv * 64 + pt * 16 + row16) << 5) + (quad << 3));
#pragma unroll
                for (int ot = 0; ot < 9; ++ot) {
                    const half8 af = *(const half8*)(wt + ((ot * 16 + row16) << 5) + (quad << 3));
#pragma unroll
                    for (int pt = 0; pt < 4; ++pt)
                        acc[pt][ot] = __builtin_amdgcn_mfma_f32_16x16x32_f16(af, bf[pt], acc[pt][ot], 0, 0, 0);
                }
            }
            __syncthreads();
        }
    }

    // ---- epilogue: wave-private LDS region, 16 pix x 144 oc' fp32 per pass ----
    float* epi = (float*)smem + wv * 2304;
    float lad_acc = 0.f;
#pragma unroll 1
    for (int pt = 0; pt < 4; ++pt) {
#pragma unroll
        for (int ot = 0; ot < 9; ++ot)
            *(f32x4*)(epi + row16 * 144 + ot * 16 + quad * 4) = acc[pt][ot];
#pragma unroll 1
        for (int pass = 0; pass < 2; ++pass) {
            const int idx = pass * 64 + lane;
            if (idx < 96) {
                const int p16 = idx & 15, c = idx >> 4;       // c 0..5
                float prm[23];
#pragma unroll
                for (int j = 0; j < 23; ++j)
                    prm[j] = epi[p16 * 144 + c * 24 + j] + b3l[c * 24 + j];
                const int tpix = wv * 64 + pt * 16 + p16;
                const size_t xi = (((size_t)(b * 12 + col * 6 + c)) << 12) + (pim0 + tpix);
                const float xv = x[xi];
                float yv, lad;
                rqs_eval(prm, xv, yv, lad);
                y[xi] = yv;
                lad_acc += lad;
            }
        }
        __syncthreads();   // protect epi region reuse across pt (and waves share smem array)
    }

#pragma unroll
    for (int off = 32; off > 0; off >>= 1) lad_acc += __shfl_down(lad_acc, off);
    if (lane == 0) atomicAdd(&ld_out[b], lad_acc);
}

// ---------------------------------------------------------------------------
extern "C" void kernel_launch(void* const* d_in, const int* in_sizes, int n_in,
                              void* d_out, int out_size, void* d_ws, size_t ws_size,
                              hipStream_t stream)
{
    const float* x      = (const float*)d_in[0];
    const float* logdet = (const float*)d_in[1];
    const float* cond   = (const float*)d_in[2];
    const float* w1     = (const float*)d_in[3];
    const float* b1     = (const float*)d_in[4];
    const float* w2     = (const float*)d_in[5];
    const float* b2     = (const float*)d_in[6];
    const float* w3     = (const float*)d_in[7];
    const float* b3     = (const float*)d_in[8];

    char* ws = (char*)d_ws;
    _Float16* h1h = (_Float16*)ws;                       // 33,554,432 B
    _Float16* h2p = (_Float16*)(ws + 33554432);          // 35,684,352 B
    float*    w1t = (float*)(ws + 69238784);             // 73,728 B
    float*    w2t = (float*)(ws + 69312512);             // 65,536 B
    _Float16* w3h = (_Float16*)(ws + 69378048);          // 663,552 B  (end ~70 MB)

    float* y      = (float*)d_out;                       // NY floats
    float* ld_out = y + NY;                              // 32 floats

    prep_k<<<1296, 256, 0, stream>>>(w1, w2, w3, w1t, w2t, w3h, logdet, ld_out);
    zring_k<<<520, 256, 0, stream>>>(h2p);
    conv1_k<<<dim3(8, 64, 32), 64, 0, stream>>>(x, cond, w1t, b1, h1h);
    conv2_k<<<dim3(8, 512), 256, 0, stream>>>(h1h, w2t, b2, h2p);
    conv3_rqs_k<<<dim3(2, 512), 256, 0, stream>>>(h2p, w3h, b3, x, y, ld_out);
}

// Round 4
// 432.269 us; speedup vs baseline: 5.2523x; 1.7615x over previous
//
#include <hip/hip_runtime.h>
#include <math.h>

// B=32, C=12, H=64, W=64, hidden=128, cond_c=4, out_spline=276 (pad->288=12*24)
// NUM_BINS=8, TAIL=3.0, MBW=MBH=MD=0.001

#define NPIX 4096
#define NY   1572864

typedef _Float16 half8 __attribute__((ext_vector_type(8)));
typedef float f32x4 __attribute__((ext_vector_type(4)));

// h2p layout: [b][cc=ci/32][pp=66*66][ci%32] fp16, halo ring of zeros
#define H2P_PLANE 4356            // 66*66
#define H2P_IDX(b, cc, pp) ((((size_t)(b) * 4 + (cc)) * H2P_PLANE + (pp)) << 5)

// ---------------------------------------------------------------------------
// prep: weight transposes + fp16 weight pack + logdet init
//   w1 (128,16,3,3)  -> w1t[(ci*9+tap)*128 + oc]                       fp32
//   w2 (128,128,1,1) -> w2t[ci*128 + oc]                               fp32
//   w3 (276,128,3,3) -> w3h[((t*4+cc)*288 + oc')*32 + cim]             fp16
//                       oc' = c*24 + j (j<23 real, j=23 zero pad)
// ---------------------------------------------------------------------------
__global__ __launch_bounds__(256) void prep_k(
    const float* __restrict__ w1, const float* __restrict__ w2,
    const float* __restrict__ w3, float* __restrict__ w1t,
    float* __restrict__ w2t, _Float16* __restrict__ w3h,
    const float* __restrict__ logdet, float* __restrict__ ld_out)
{
    const int i = blockIdx.x * 256 + threadIdx.x;   // < 331776
    if (i < 18432) {
        int oc = i / 144, r = i % 144;
        w1t[r * 128 + oc] = w1[i];
    }
    if (i < 16384) {
        int oc = i >> 7, ci = i & 127;
        w2t[ci * 128 + oc] = w2[i];
    }
    {   // w3h: flat i = ((t*4+cc)*288 + oc)*32 + cim
        int cim = i & 31;
        int oc = (i >> 5) % 288;
        int tc = i / (288 * 32);        // 0..35
        int t = tc >> 2, cc = tc & 3;
        int c = oc / 24, j = oc % 24;
        int ci = cc * 32 + cim;
        float v = (j < 23) ? w3[((c * 23 + j) * 128 + ci) * 9 + t] : 0.f;
        w3h[i] = (_Float16)v;
    }
    if (i < 32) ld_out[i] = logdet[i];
}

// ---------------------------------------------------------------------------
// zero the halo ring of h2p (260 border pixels per (b,cc) plane)
// ---------------------------------------------------------------------------
__global__ __launch_bounds__(256) void zring_k(_Float16* __restrict__ h2p)
{
    const int i = blockIdx.x * 256 + threadIdx.x;
    if (i >= 133120) return;
    const int q = i & 3;
    const int rest = i >> 2;
    const int r = rest % 260;
    const int cc = (rest / 260) & 3;
    const int b = rest / 1040;
    int pp;
    if (r < 66)       pp = r;                        // top row
    else if (r < 132) pp = 65 * 66 + (r - 66);       // bottom row
    else if (r < 196) pp = (r - 131) * 66;           // left col, rows 1..64
    else              pp = (r - 195) * 66 + 65;      // right col, rows 1..64
    f32x4 z = {0.f, 0.f, 0.f, 0.f};
    *(f32x4*)(h2p + H2P_IDX(b, cc, pp) + q * 8) = z;
}

// ---------------------------------------------------------------------------
// conv1: 3x3 SAME, in=concat(x[12], cond[4]), out=128, +bias+relu -> h1h fp16
// ---------------------------------------------------------------------------
__global__ __launch_bounds__(64) void conv1_k(
    const float* __restrict__ x, const float* __restrict__ cond,
    const float* __restrict__ w1t, const float* __restrict__ b1,
    _Float16* __restrict__ h1h)
{
    const int w = threadIdx.x;
    const int ocb = blockIdx.x * 16;
    const int h = blockIdx.y;
    const int b = blockIdx.z;

    float acc[16];
#pragma unroll
    for (int j = 0; j < 16; ++j) acc[j] = b1[ocb + j];

    for (int ci = 0; ci < 16; ++ci) {
        const float* src = (ci < 12) ? (x + ((size_t)(b * 12 + ci)) * NPIX)
                                     : (cond + ((size_t)(b * 4 + (ci - 12))) * NPIX);
#pragma unroll
        for (int dy = -1; dy <= 1; ++dy) {
            const int hh = h + dy;
            const bool hv = (hh >= 0) && (hh < 64);
#pragma unroll
            for (int dx = -1; dx <= 1; ++dx) {
                const int ww = w + dx;
                const float v = (hv && ww >= 0 && ww < 64) ? src[hh * 64 + ww] : 0.f;
                const float* wp = w1t + (ci * 9 + (dy + 1) * 3 + (dx + 1)) * 128 + ocb;
#pragma unroll
                for (int j = 0; j < 16; ++j) acc[j] = fmaf(v, wp[j], acc[j]);
            }
        }
    }
#pragma unroll
    for (int j = 0; j < 16; ++j)
        h1h[(((size_t)(b * 128 + ocb + j)) << 12) + h * 64 + w] = (_Float16)fmaxf(acc[j], 0.f);
}

// ---------------------------------------------------------------------------
// conv2: 1x1, 128->128, +bias+relu; reads h1h fp16, writes h2p fp16 (padded)
// ---------------------------------------------------------------------------
__global__ __launch_bounds__(256) void conv2_k(
    const _Float16* __restrict__ h1h, const float* __restrict__ w2t,
    const float* __restrict__ b2, _Float16* __restrict__ h2p)
{
    const int ocb = blockIdx.x * 16;
    const int pg = blockIdx.y * 256 + threadIdx.x;
    const int b = pg >> 12;
    const int p = pg & 4095;

    float acc[16];
#pragma unroll
    for (int j = 0; j < 16; ++j) acc[j] = b2[ocb + j];

    for (int ci = 0; ci < 128; ++ci) {
        const float v = (float)h1h[(((size_t)(b * 128 + ci)) << 12) + p];
        const float* wp = w2t + ci * 128 + ocb;
#pragma unroll
        for (int j = 0; j < 16; ++j) acc[j] = fmaf(v, wp[j], acc[j]);
    }

    const int h = p >> 6, w = p & 63;
    const int pp = (h + 1) * 66 + (w + 1);
    const int cc = ocb >> 5;
    _Float16 tmp[16];
#pragma unroll
    for (int j = 0; j < 16; ++j) tmp[j] = (_Float16)fmaxf(acc[j], 0.f);
    _Float16* dst = h2p + H2P_IDX(b, cc, pp) + (ocb & 31);
    *(f32x4*)(dst)     = *(f32x4*)(tmp);
    *(f32x4*)(dst + 8) = *(f32x4*)(tmp + 8);
}

// ---------------------------------------------------------------------------
// RQS spline evaluation for one element, given its 23 params in prm[].
// ---------------------------------------------------------------------------
__device__ __forceinline__ void rqs_eval(const float* prm, float xv,
                                         float& yv_out, float& lad_out)
{
    const float xin = fminf(fmaxf(xv, -3.f), 3.f);

    float mw = prm[0], mh = prm[8];
#pragma unroll
    for (int j = 1; j < 8; ++j) { mw = fmaxf(mw, prm[j]); mh = fmaxf(mh, prm[8 + j]); }
    float ew[8], eh[8];
    float sw = 0.f, sh = 0.f;
#pragma unroll
    for (int j = 0; j < 8; ++j) {
        ew[j] = expf(prm[j] - mw);      sw += ew[j];
        eh[j] = expf(prm[8 + j] - mh);  sh += eh[j];
    }
    const float rw = 1.f / sw, rh = 1.f / sh;

    const float CONST_D = logf(expf(0.999f) - 1.f);

    float cumw = 0.f, cumh = 0.f;
    float cw_lo = -3.f, ch_lo = -3.f;
    float in_cw = 0.f, in_w = 1.f, in_ch = 0.f, in_h = 1.f, sd0 = 0.f, sd1 = 0.f;
#pragma unroll
    for (int i = 0; i < 8; ++i) {
        cumw += fmaf(0.992f, ew[i] * rw, 0.001f);
        cumh += fmaf(0.992f, eh[i] * rh, 0.001f);
        const float cw_hi = (i == 7) ? 3.f : fmaf(6.f, cumw, -3.f);
        const float ch_hi = (i == 7) ? 3.f : fmaf(6.f, cumh, -3.f);
        const bool sel = (xin >= cw_lo) && ((i == 7) || (xin < cw_hi));
        in_cw = sel ? cw_lo : in_cw;
        in_w  = sel ? (cw_hi - cw_lo) : in_w;
        in_ch = sel ? ch_lo : in_ch;
        in_h  = sel ? (ch_hi - ch_lo) : in_h;
        sd0   = sel ? ((i == 0) ? CONST_D : prm[16 + i - 1]) : sd0;
        sd1   = sel ? ((i == 7) ? CONST_D : prm[16 + i]) : sd1;
        cw_lo = cw_hi; ch_lo = ch_hi;
    }

    const float d0 = 0.001f + ((sd0 > 20.f) ? sd0 : log1pf(expf(sd0)));
    const float d1 = 0.001f + ((sd1 > 20.f) ? sd1 : log1pf(expf(sd1)));

    const float delta = in_h / in_w;
    const float theta = (xin - in_cw) / in_w;
    const float omt = 1.f - theta;
    const float tom = theta * omt;
    const float th2 = theta * theta;
    const float numer = in_h * (delta * th2 + d0 * tom);
    const float denom = delta + (d0 + d1 - 2.f * delta) * tom;
    float yv = in_ch + numer / denom;
    const float dnum = delta * delta * (d1 * th2 + 2.f * delta * tom + d0 * omt * omt);
    float lad = logf(dnum) - 2.f * logf(denom);

    const bool inside = (xv >= -3.f) && (xv <= 3.f);
    yv_out = inside ? yv : xv;
    lad_out = inside ? lad : 0.f;
}

// ---------------------------------------------------------------------------
// conv3 as implicit-GEMM MFMA, v2: barrier-free K-loop, direct global->VGPR
// fragments (both A and B fragment patterns are perfectly coalesced 1KB/wave
// loads), no LDS staging, no spill (144 acc + 52 frag + temps < 256 unified).
// GEMM: M=pixels (tile 256), N=oc' 288 (2 cols x 144), K=1152 (9 taps x 128 ci)
// WG = 256 threads (4 waves). Wave wv: pixels [wv*64, wv*64+64) x 144 oc'
//   = 4 pix-tiles x 9 oc-tiles of 16x16x32 MFMA; acc = 144 VGPRs.
// Tap/col redundancy (~2 GB frag reads) is served by L2 (weights 648 KB hot,
// block act working set 68 KB). Epilogue: LDS round-trip + RQS (as round 3).
// ---------------------------------------------------------------------------
__global__ __launch_bounds__(256, 2) void conv3_rqs_k(
    const _Float16* __restrict__ h2p, const _Float16* __restrict__ w3h,
    const float* __restrict__ b3, const float* __restrict__ x,
    float* __restrict__ y, float* __restrict__ ld_out)
{
    __shared__ __align__(16) float epi_smem[4 * 2304];   // 36864 B, epilogue only
    __shared__ float b3l[144];

    const int tid = threadIdx.x;
    const int wv = tid >> 6, lane = tid & 63;
    const int row16 = lane & 15, quad = lane >> 4;
    const int col = blockIdx.x;            // 0..1 -> oc' base col*144, channels col*6..+5
    const int pix0 = blockIdx.y << 8;      // global pixel base (256-tile)
    const int b = pix0 >> 12;
    const int pim0 = pix0 & 4095;          // within-image
    const int h0 = pim0 >> 6;              // base row (multiple of 4)

    if (tid < 144) {
        const int c = tid / 24, j = tid % 24;
        b3l[tid] = (j < 23) ? b3[(col * 6 + c) * 23 + j] : 0.f;
    }

    f32x4 acc[4][9];
#pragma unroll
    for (int pt = 0; pt < 4; ++pt)
#pragma unroll
        for (int ot = 0; ot < 9; ++ot) acc[pt][ot] = (f32x4){0.f, 0.f, 0.f, 0.f};

    // Wave's output row = h0 + wv; B-frag lane (row16,quad) holds
    // B[k=quad*8+j][n=row16] => pixel col pt*16+row16, ci quad*8+j.
    // A-frag lane holds A[m=row16][k=quad*8+j] => oc ot*16+row16, ci quad*8+j.
    for (int t = 0; t < 9; ++t) {
        const int dy = t / 3 - 1, dx = t % 3 - 1;
        const int prow = h0 + wv + dy + 1;               // padded source row
        const int pbase = prow * 66 + dx + 1 + row16;    // + pixel col offset
#pragma unroll
        for (int cc = 0; cc < 4; ++cc) {
            half8 bf[4], af[9];
#pragma unroll
            for (int pt = 0; pt < 4; ++pt)
                bf[pt] = *(const half8*)(h2p + H2P_IDX(b, cc, pbase + pt * 16) + quad * 8);
            const _Float16* gw = w3h + ((size_t)((t * 4 + cc) * 288 + col * 144) << 5);
#pragma unroll
            for (int ot = 0; ot < 9; ++ot)
                af[ot] = *(const half8*)(gw + ((ot * 16 + row16) << 5) + quad * 8);
#pragma unroll
            for (int ot = 0; ot < 9; ++ot)
#pragma unroll
                for (int pt = 0; pt < 4; ++pt)
                    acc[pt][ot] = __builtin_amdgcn_mfma_f32_16x16x32_f16(af[ot], bf[pt], acc[pt][ot], 0, 0, 0);
        }
    }

    __syncthreads();   // b3l visible; epi region about to be used

    // ---- epilogue: wave-private LDS region, 16 pix x 144 oc' fp32 per pass ----
    float* epi = epi_smem + wv * 2304;
    float lad_acc = 0.f;
#pragma unroll 1
    for (int pt = 0; pt < 4; ++pt) {
#pragma unroll
        for (int ot = 0; ot < 9; ++ot)
            *(f32x4*)(epi + row16 * 144 + ot * 16 + quad * 4) = acc[pt][ot];
#pragma unroll 1
        for (int pass = 0; pass < 2; ++pass) {
            const int idx = pass * 64 + lane;
            if (idx < 96) {
                const int p16 = idx & 15, c = idx >> 4;       // c 0..5
                float prm[23];
#pragma unroll
                for (int j = 0; j < 23; ++j)
                    prm[j] = epi[p16 * 144 + c * 24 + j] + b3l[c * 24 + j];
                const int tpix = wv * 64 + pt * 16 + p16;
                const size_t xi = (((size_t)(b * 12 + col * 6 + c)) << 12) + (pim0 + tpix);
                const float xv = x[xi];
                float yv, lad;
                rqs_eval(prm, xv, yv, lad);
                y[xi] = yv;
                lad_acc += lad;
            }
        }
        __syncthreads();   // epi region reuse across pt
    }

#pragma unroll
    for (int off = 32; off > 0; off >>= 1) lad_acc += __shfl_down(lad_acc, off);
    if (lane == 0) atomicAdd(&ld_out[b], lad_acc);
}

// ---------------------------------------------------------------------------
extern "C" void kernel_launch(void* const* d_in, const int* in_sizes, int n_in,
                              void* d_out, int out_size, void* d_ws, size_t ws_size,
                              hipStream_t stream)
{
    const float* x      = (const float*)d_in[0];
    const float* logdet = (const float*)d_in[1];
    const float* cond   = (const float*)d_in[2];
    const float* w1     = (const float*)d_in[3];
    const float* b1     = (const float*)d_in[4];
    const float* w2     = (const float*)d_in[5];
    const float* b2     = (const float*)d_in[6];
    const float* w3     = (const float*)d_in[7];
    const float* b3     = (const float*)d_in[8];

    char* ws = (char*)d_ws;
    _Float16* h1h = (_Float16*)ws;                       // 33,554,432 B
    _Float16* h2p = (_Float16*)(ws + 33554432);          // 35,684,352 B
    float*    w1t = (float*)(ws + 69238784);             // 73,728 B
    float*    w2t = (float*)(ws + 69312512);             // 65,536 B
    _Float16* w3h = (_Float16*)(ws + 69378048);          // 663,552 B  (end ~70 MB)

    float* y      = (float*)d_out;                       // NY floats
    float* ld_out = y + NY;                              // 32 floats

    prep_k<<<1296, 256, 0, stream>>>(w1, w2, w3, w1t, w2t, w3h, logdet, ld_out);
    zring_k<<<520, 256, 0, stream>>>(h2p);
    conv1_k<<<dim3(8, 64, 32), 64, 0, stream>>>(x, cond, w1t, b1, h1h);
    conv2_k<<<dim3(8, 512), 256, 0, stream>>>(h1h, w2t, b2, h2p);
    conv3_rqs_k<<<dim3(2, 512), 256, 0, stream>>>(h2p, w3h, b3, x, y, ld_out);
}